// Round 7
// baseline (117.709 us; speedup 1.0000x reference)
//
#include <hip/hip_runtime.h>
#include <math.h>

#define PH 7
#define PW 7
#define B_ 4
#define C_ 256
#define H_ 50
#define W_ 50
#define R_ 256
#define S_ (H_ * W_)     // 2500
#define NCELL (PH * PW)  // 49
#define MAXW 9           // max window width: ceil(50/7)+1
#define REP 4            // DIAGNOSTIC: repeat K2 body so it exceeds the 45us
                         // fills and surfaces in rocprof top-5 WITH counters.

// ---------- kernel 1: features (B,C,H,W) -> (B,H,W,C) ----------
__global__ void transpose_chw_hwc(const float* __restrict__ in, float* __restrict__ out) {
    __shared__ float tile[32][33];
    const int b  = blockIdx.z;
    const int s0 = blockIdx.x * 32;
    const int c0 = blockIdx.y * 32;
    const float* inb  = in  + (size_t)b * C_ * S_;
    float*       outb = out + (size_t)b * S_ * C_;
    const int tx = threadIdx.x;
    #pragma unroll
    for (int i = threadIdx.y; i < 32; i += 8) {
        const int s = s0 + tx;
        if (s < S_) tile[i][tx] = inb[(size_t)(c0 + i) * S_ + s];
    }
    __syncthreads();
    #pragma unroll
    for (int i = threadIdx.y; i < 32; i += 8) {
        const int s = s0 + i;
        if (s < S_) outb[(size_t)s * C_ + (c0 + tx)] = tile[tx][i];
    }
}

__device__ __forceinline__ float4 max4(float4 a, float4 b) {
    a.x = fmaxf(a.x, b.x); a.y = fmaxf(a.y, b.y);
    a.z = fmaxf(a.z, b.z); a.w = fmaxf(a.w, b.w);
    return a;
}

// ---------- kernel 2: pool. One wave per (cell, roi). ----------
// IDENTICAL to the round-3 (90.1us) kernel except the REP diagnostic loop:
// body repeated 4x (idempotent store; memory clobber blocks cross-rep CSE)
// so this dispatch exceeds the 45us harness fills and appears in top-5 with
// real counters (VGPR/occupancy/VALUBusy/FETCH). dur/4 ~= true K2 cost.
__global__ void __launch_bounds__(64, 4)
roi_pool_cell(const float* __restrict__ ft, const int* __restrict__ rois,
              float* __restrict__ tmp) {
    const int bx   = blockIdx.x;
    const int cell = bx >> 8;        // 0..48
    const int r    = bx & 255;       // 0..255
    const int lane = threadIdx.x;    // 0..63

    const int* roi = rois + r * 5;
    const int b  = roi[0];
    const int x1 = roi[1] >> 4;   // floor(v/16), v >= 0
    const int y1 = roi[2] >> 4;
    const int x2 = roi[3] >> 4;
    const int y2 = roi[4] >> 4;
    const int h = y2 - y1 + 1;
    const int w = x2 - x1 + 1;

    const int ph = cell / PW;
    const int pw = cell - ph * PW;
    const int sh = y1 + (ph * h) / PH;
    const int eh = y1 + ((ph + 1) * h + PH - 1) / PH;
    const int sw = x1 + (pw * w) / PW;
    const int ew = x1 + ((pw + 1) * w + PW - 1) / PW;
    const int kw = ew - sw;          // 1..9, wave-uniform

    const float* fb = ft + (size_t)b * S_ * C_ + 4 * lane;

    #pragma unroll 1
    for (int rep = 0; rep < REP; ++rep) {
        float4 acc = make_float4(-INFINITY, -INFINITY, -INFINITY, -INFINITY);

        int y = sh;
        if ((eh - sh) & 1) {             // odd band height: single-row prologue
            const float* p0 = fb + (size_t)(y * W_ + sw) * C_;
            float4 v0[MAXW];
            #pragma unroll
            for (int k = 0; k < MAXW; ++k)
                if (k < kw) v0[k] = *(const float4*)(p0 + (size_t)k * C_);
            #pragma unroll
            for (int k = 0; k < MAXW; ++k)
                if (k < kw) acc = max4(acc, v0[k]);
            ++y;
        }
        for (; y < eh; y += 2) {         // even remainder: true row pairs
            const float* p0 = fb + (size_t)( y      * W_ + sw) * C_;
            const float* p1 = fb + (size_t)((y + 1) * W_ + sw) * C_;
            float4 v0[MAXW], v1[MAXW];
            #pragma unroll
            for (int k = 0; k < MAXW; ++k) {
                if (k < kw) {                            // wave-uniform branch
                    v0[k] = *(const float4*)(p0 + (size_t)k * C_);
                    v1[k] = *(const float4*)(p1 + (size_t)k * C_);
                }
            }
            #pragma unroll
            for (int k = 0; k < MAXW; ++k) {
                if (k < kw) acc = max4(acc, max4(v0[k], v1[k]));
            }
        }

        *(float4*)(tmp + ((size_t)(r * NCELL + cell)) * C_ + 4 * lane) = acc;
        asm volatile("" ::: "memory");   // block cross-rep load CSE
    }
}

// ---------- kernel 3: tmp (R,49,C) -> out (R,C,49) ----------
__global__ void __launch_bounds__(256)
transpose_out(const float* __restrict__ tmp, float* __restrict__ out) {
    __shared__ float lds[NCELL * 129];  // 25.3 KB
    const int r    = blockIdx.x >> 1;
    const int c0   = (blockIdx.x & 1) << 7;   // 0 or 128
    const int t    = threadIdx.x;
    const float* src = tmp + (size_t)r * NCELL * C_ + c0;
    float*       dst = out + (size_t)r * C_ * NCELL + (size_t)c0 * NCELL;

    #pragma unroll
    for (int i = t; i < NCELL * 128; i += 256) {
        const int cell = i >> 7;         // i = cell*128 + c
        const int c    = i & 127;
        lds[cell * 129 + c] = src[(size_t)cell * C_ + c];
    }
    __syncthreads();
    #pragma unroll
    for (int f = t; f < 128 * NCELL; f += 256) {
        const int c    = f / NCELL;      // const divisor -> magic mul
        const int cell = f - c * NCELL;  // f = c*49 + cell
        dst[f] = lds[cell * 129 + c];
    }
}

extern "C" void kernel_launch(void* const* d_in, const int* in_sizes, int n_in,
                              void* d_out, int out_size, void* d_ws, size_t ws_size,
                              hipStream_t stream) {
    const float* features = (const float*)d_in[0];
    const int*   rois     = (const int*)d_in[1];
    float*       out      = (float*)d_out;

    float* ft  = (float*)d_ws;                       // 10.24 MB
    float* tmp = ft + (size_t)B_ * S_ * C_;          // +12.85 MB (ws is 256 MB)

    dim3 tgrid((S_ + 31) / 32, C_ / 32, B_);
    transpose_chw_hwc<<<tgrid, dim3(32, 8), 0, stream>>>(features, ft);
    roi_pool_cell<<<NCELL * R_, 64, 0, stream>>>(ft, rois, tmp);
    transpose_out<<<R_ * 2, 256, 0, stream>>>(tmp, out);
}

// Round 8
// 105.846 us; speedup vs baseline: 1.1121x; 1.1121x over previous
//
#include <hip/hip_runtime.h>
#include <math.h>

#define PH 7
#define PW 7
#define B_ 4
#define C_ 256
#define H_ 50
#define W_ 50
#define R_ 256
#define S_ (H_ * W_)     // 2500
#define NCELL (PH * PW)  // 49
#define MAXW 9           // max window width: ceil(50/7)+1
#define LDSP 129         // [49][128] tile stride; 129%32==1 -> conflict-free

// ---------- kernel 1: features (B,C,H,W) -> (B,H,W,C) ----------
__global__ void transpose_chw_hwc(const float* __restrict__ in, float* __restrict__ out) {
    __shared__ float tile[32][33];
    const int b  = blockIdx.z;
    const int s0 = blockIdx.x * 32;
    const int c0 = blockIdx.y * 32;
    const float* inb  = in  + (size_t)b * C_ * S_;
    float*       outb = out + (size_t)b * S_ * C_;
    const int tx = threadIdx.x;
    #pragma unroll
    for (int i = threadIdx.y; i < 32; i += 8) {
        const int s = s0 + tx;
        if (s < S_) tile[i][tx] = inb[(size_t)(c0 + i) * S_ + s];
    }
    __syncthreads();
    #pragma unroll
    for (int i = threadIdx.y; i < 32; i += 8) {
        const int s = s0 + i;
        if (s < S_) outb[(size_t)s * C_ + (c0 + tx)] = tile[tx][i];
    }
}

__device__ __forceinline__ float2 max2(float2 a, float2 b) {
    a.x = fmaxf(a.x, b.x); a.y = fmaxf(a.y, b.y);
    return a;
}

// ---------- kernel 2 (fused K2+K3): pool + output transpose ----------
// Block = (roi, 128-channel half): 512 blocks x 512 threads (8 waves,
// 2 blocks/CU, 16 waves/CU). Wave w processes cells w, w+8, ... with the
// round-3 proven inner loop, float2 per lane (512 B coalesced wave-loads,
// same total bytes as the float4 version — K2 measured cache-BW-bound at
// ~9 us, so extra load instructions are free). Results staged in the K3
// proven [49][129] LDS tile; write phase coalesced. Removes: one dispatch
// gap (~6 us), the 25.7 MB tmp round-trip, K3's standalone tail.
__global__ void __launch_bounds__(512, 4)
roi_pool_fused(const float* __restrict__ ft, const int* __restrict__ rois,
               float* __restrict__ out) {
    __shared__ float lds[NCELL * LDSP];   // 25.3 KB
    const int r    = blockIdx.x >> 1;     // 0..255
    const int c0   = (blockIdx.x & 1) << 7;   // 0 or 128
    const int wid  = threadIdx.x >> 6;    // 0..7
    const int lane = threadIdx.x & 63;    // 0..63

    const int* roi = rois + r * 5;
    const int b  = roi[0];
    const int x1 = roi[1] >> 4;   // floor(v/16), v >= 0
    const int y1 = roi[2] >> 4;
    const int x2 = roi[3] >> 4;
    const int y2 = roi[4] >> 4;
    const int h = y2 - y1 + 1;
    const int w = x2 - x1 + 1;

    const float* fb = ft + (size_t)b * S_ * C_ + c0 + 2 * lane;

    for (int cell = wid; cell < NCELL; cell += 8) {
        const int ph = cell / PW;
        const int pw = cell - ph * PW;
        const int sh = y1 + (ph * h) / PH;
        const int eh = y1 + ((ph + 1) * h + PH - 1) / PH;
        const int sw = x1 + (pw * w) / PW;
        const int ew = x1 + ((pw + 1) * w + PW - 1) / PW;
        const int kw = ew - sw;          // 1..9, wave-uniform

        float2 acc = make_float2(-INFINITY, -INFINITY);

        int y = sh;
        if ((eh - sh) & 1) {             // odd band height: single-row prologue
            const float* p0 = fb + (size_t)(y * W_ + sw) * C_;
            float2 v0[MAXW];
            #pragma unroll
            for (int k = 0; k < MAXW; ++k)
                if (k < kw) v0[k] = *(const float2*)(p0 + (size_t)k * C_);
            #pragma unroll
            for (int k = 0; k < MAXW; ++k)
                if (k < kw) acc = max2(acc, v0[k]);
            ++y;
        }
        for (; y < eh; y += 2) {         // even remainder: true row pairs
            const float* p0 = fb + (size_t)( y      * W_ + sw) * C_;
            const float* p1 = fb + (size_t)((y + 1) * W_ + sw) * C_;
            float2 v0[MAXW], v1[MAXW];
            #pragma unroll
            for (int k = 0; k < MAXW; ++k) {
                if (k < kw) {                        // wave-uniform branch
                    v0[k] = *(const float2*)(p0 + (size_t)k * C_);
                    v1[k] = *(const float2*)(p1 + (size_t)k * C_);
                }
            }
            #pragma unroll
            for (int k = 0; k < MAXW; ++k) {
                if (k < kw) acc = max2(acc, max2(v0[k], v1[k]));
            }
        }

        lds[cell * LDSP + 2 * lane]     = acc.x;   // 2-way bank alias: free
        lds[cell * LDSP + 2 * lane + 1] = acc.y;
    }

    __syncthreads();

    // out (R,C,49): this block owns channels [c0, c0+128) of roi r.
    float* dst = out + (size_t)r * C_ * NCELL + (size_t)c0 * NCELL;
    #pragma unroll
    for (int f = threadIdx.x; f < 128 * NCELL; f += 512) {
        const int c    = f / NCELL;      // const divisor -> magic mul
        const int cell = f - c * NCELL;  // f = c*49 + cell
        dst[f] = lds[cell * LDSP + c];   // bank stride 1: conflict-free
    }
}

extern "C" void kernel_launch(void* const* d_in, const int* in_sizes, int n_in,
                              void* d_out, int out_size, void* d_ws, size_t ws_size,
                              hipStream_t stream) {
    const float* features = (const float*)d_in[0];
    const int*   rois     = (const int*)d_in[1];
    float*       out      = (float*)d_out;

    float* ft = (float*)d_ws;                        // 10.24 MB (ws is 256 MB)

    dim3 tgrid((S_ + 31) / 32, C_ / 32, B_);
    transpose_chw_hwc<<<tgrid, dim3(32, 8), 0, stream>>>(features, ft);
    roi_pool_fused<<<R_ * 2, 512, 0, stream>>>(ft, rois, out);
}